// Round 12
// baseline (2949.754 us; speedup 1.0000x reference)
//
#include <hip/hip_runtime.h>
#include <hip/hip_bf16.h>
#include <math.h>

#define Bn 64
#define Tn 2048
#define Hn 256

constexpr float LEAK    = 0.5f;     // 1 - 1/TAU
constexpr float NEGDIAG = -0.5f;    // -1/TAU
constexpr float CLAMP_V = 1000.0f;
constexpr float EPS_V   = 1e-4f;

typedef __attribute__((ext_vector_type(8))) short  short8;  // 8 bf16 (4 VGPR)
typedef __attribute__((ext_vector_type(4))) float  f32x4;

#define FAST_BARRIER() do {                                   \
    asm volatile("s_waitcnt lgkmcnt(0)" ::: "memory");        \
    __builtin_amdgcn_s_barrier();                             \
    asm volatile("" ::: "memory");                            \
  } while (0)

__device__ inline short bf16_rne(float x) {
  __hip_bfloat16 h = __float2bfloat16(x);
  return *reinterpret_cast<short*>(&h);
}
__device__ inline float bf16_to_f(short s) {
  union { unsigned u; float f; } c; c.u = ((unsigned)(unsigned short)s) << 16;
  return c.f;
}
__device__ inline unsigned pack2(short a, short b) {
  return (unsigned)(unsigned short)a | ((unsigned)(unsigned short)b << 16);
}

// LDS row stride for bf16 tiles: 32 k + 8 pad = 40 shorts (80 B, 16B-multiple)
#define SA 40

// ---------------------------------------------------------------------------
// G1: u = relu(inp8 @ W1^T + b1) @ Wih^T, MFMA bf16 hi/lo. (unchanged, passing)
// ---------------------------------------------------------------------------
__global__ __launch_bounds__(512) void g_u(
    const float* __restrict__ reward, const float* __restrict__ state,
    const float* __restrict__ last_action, const float* __restrict__ W1,
    const float* __restrict__ b1, const float* __restrict__ Wih,
    float* __restrict__ u)
{
  __shared__ short Ah[128*SA], Al[128*SA], Bh[256*SA], Bl[256*SA];
  __shared__ __align__(16) float inp_s[128][8];
  __shared__ __align__(16) float w1_s[256][8];
  __shared__ float b1_s[256];
  const int tid = threadIdx.x;
  const int r0  = blockIdx.x * 128;

  for (int idx = tid; idx < 2048; idx += 512) ((float*)w1_s)[idx] = W1[idx];
  if (tid < 256) b1_s[tid] = b1[tid];
  for (int idx = tid; idx < 1024; idx += 512) {
    int rr = idx >> 3, i = idx & 7;
    int r = r0 + rr, b = r & 63, t = r >> 6;
    long base = (long)b * Tn + t;
    float v;
    if (i < 2)      v = reward[base * 2 + i];
    else if (i < 6) v = state[base * 4 + (i - 2)];
    else            v = last_action[base * 2 + (i - 6)];
    inp_s[rr][i] = v;
  }

  const int w    = tid >> 6, lane = tid & 63;
  const int wm   = w >> 2, wn = w & 3;
  const int fr   = lane & 15, fk = lane >> 4;
  f32x4 acc[4][4];
  #pragma unroll
  for (int a = 0; a < 4; ++a)
    #pragma unroll
    for (int c = 0; c < 4; ++c) acc[a][c] = (f32x4){0.f, 0.f, 0.f, 0.f};

  __syncthreads();

  for (int ks = 0; ks < 8; ++ks) {
    const int k0 = ks * 32;
    if (ks) __syncthreads();
    for (int p = tid; p < 2048; p += 512) {
      int rr = p >> 4, kp = (p & 15) * 2;
      int k = k0 + kp;
      float4 iv0 = *reinterpret_cast<const float4*>(&inp_s[rr][0]);
      float4 iv1 = *reinterpret_cast<const float4*>(&inp_s[rr][4]);
      float4 wa0 = *reinterpret_cast<const float4*>(&w1_s[k][0]);
      float4 wa1 = *reinterpret_cast<const float4*>(&w1_s[k][4]);
      float4 wb0 = *reinterpret_cast<const float4*>(&w1_s[k+1][0]);
      float4 wb1 = *reinterpret_cast<const float4*>(&w1_s[k+1][4]);
      float s0 = b1_s[k], s1 = b1_s[k+1];
      s0 = fmaf(iv0.x, wa0.x, s0); s0 = fmaf(iv0.y, wa0.y, s0);
      s0 = fmaf(iv0.z, wa0.z, s0); s0 = fmaf(iv0.w, wa0.w, s0);
      s0 = fmaf(iv1.x, wa1.x, s0); s0 = fmaf(iv1.y, wa1.y, s0);
      s0 = fmaf(iv1.z, wa1.z, s0); s0 = fmaf(iv1.w, wa1.w, s0);
      s1 = fmaf(iv0.x, wb0.x, s1); s1 = fmaf(iv0.y, wb0.y, s1);
      s1 = fmaf(iv0.z, wb0.z, s1); s1 = fmaf(iv0.w, wb0.w, s1);
      s1 = fmaf(iv1.x, wb1.x, s1); s1 = fmaf(iv1.y, wb1.y, s1);
      s1 = fmaf(iv1.z, wb1.z, s1); s1 = fmaf(iv1.w, wb1.w, s1);
      float v0 = fmaxf(s0, 0.f), v1 = fmaxf(s1, 0.f);
      short h0 = bf16_rne(v0), h1 = bf16_rne(v1);
      short l0 = bf16_rne(v0 - bf16_to_f(h0)), l1 = bf16_rne(v1 - bf16_to_f(h1));
      int off = rr * SA + kp;
      *reinterpret_cast<unsigned*>(&Ah[off]) = pack2(h0, h1);
      *reinterpret_cast<unsigned*>(&Al[off]) = pack2(l0, l1);
    }
    for (int c = tid; c < 2048; c += 512) {
      int n = c >> 3, kc = (c & 7) * 4;
      float4 f = *reinterpret_cast<const float4*>(&Wih[n * 256 + k0 + kc]);
      short h0 = bf16_rne(f.x), h1 = bf16_rne(f.y), h2 = bf16_rne(f.z), h3 = bf16_rne(f.w);
      short l0 = bf16_rne(f.x - bf16_to_f(h0)), l1 = bf16_rne(f.y - bf16_to_f(h1));
      short l2 = bf16_rne(f.z - bf16_to_f(h2)), l3 = bf16_rne(f.w - bf16_to_f(h3));
      int off = n * SA + kc;
      *reinterpret_cast<uint2*>(&Bh[off]) = make_uint2(pack2(h0, h1), pack2(h2, h3));
      *reinterpret_cast<uint2*>(&Bl[off]) = make_uint2(pack2(l0, l1), pack2(l2, l3));
    }
    __syncthreads();
    short8 bhf[4], blf[4];
    #pragma unroll
    for (int nf = 0; nf < 4; ++nf) {
      const int brow = wn * 64 + nf * 16 + fr;
      bhf[nf] = *reinterpret_cast<const short8*>(&Bh[brow * SA + fk * 8]);
      blf[nf] = *reinterpret_cast<const short8*>(&Bl[brow * SA + fk * 8]);
    }
    #pragma unroll
    for (int mf = 0; mf < 4; ++mf) {
      const int arow = wm * 64 + mf * 16 + fr;
      short8 ah = *reinterpret_cast<const short8*>(&Ah[arow * SA + fk * 8]);
      short8 al = *reinterpret_cast<const short8*>(&Al[arow * SA + fk * 8]);
      #pragma unroll
      for (int nf = 0; nf < 4; ++nf) {
        acc[mf][nf] = __builtin_amdgcn_mfma_f32_16x16x32_bf16(ah, bhf[nf], acc[mf][nf], 0, 0, 0);
        acc[mf][nf] = __builtin_amdgcn_mfma_f32_16x16x32_bf16(ah, blf[nf], acc[mf][nf], 0, 0, 0);
        acc[mf][nf] = __builtin_amdgcn_mfma_f32_16x16x32_bf16(al, bhf[nf], acc[mf][nf], 0, 0, 0);
      }
    }
  }
  #pragma unroll
  for (int mf = 0; mf < 4; ++mf) {
    const int rbase = r0 + wm * 64 + mf * 16 + (lane >> 4) * 4;
    #pragma unroll
    for (int nf = 0; nf < 4; ++nf) {
      const int n = wn * 64 + nf * 16 + fr;
      #pragma unroll
      for (int j = 0; j < 4; ++j)
        u[(long)(rbase + j) * Hn + n] = acc[mf][nf][j];
    }
  }
}

// ---------------------------------------------------------------------------
// K2 v11: round-5 MFMA scan (correctness-VERIFIED in round 5) + AGPR pinning.
// 256 thr / 4 waves (1 per SIMD). Weights = static MFMA A-fragments, hi/lo
// bf16, 64 short8 = 256 regs — PINNED to AGPRs via empty asm "+a" so the
// allocator parks them in the AGPR half of the unified file (r5 spilled to
// scratch: 224 ArchVGPR < 256 needed -> per-step reload, 2940 us).
// MFMA reads A from AGPR natively (ISA §10) — zero per-use cost.
// B = relu(h) hi/lo broadcast from 1KB LDS (double-buffered). K-reduction
// inside matrix pipe; C col 0 lands in fr==0 lanes' VGPRs; one barrier/step.
// ---------------------------------------------------------------------------
__global__ __launch_bounds__(256) void k_scan(
    const float* __restrict__ Whh_raw, const float* __restrict__ hidden_in,
    float* __restrict__ ubuf, float* __restrict__ out)
{
  __shared__ __align__(16) short rh_s[2][2][256];   // [buf][hi/lo][k]
  const int tid  = threadIdx.x;
  const int w    = tid >> 6;        // 0..3
  const int lane = tid & 63;
  const int fr   = lane & 15;       // A row / C col
  const int fk   = lane >> 4;       // k-subslice 0..3
  const int b    = blockIdx.x;
  const bool owner = (fr == 0);

  // ---- static A fragments: Whh hi/lo, diag -> NEGDIAG ----
  short8 whi[4][8], wlo[4][8];
  #pragma unroll
  for (int mt = 0; mt < 4; ++mt) {
    const int j = (w * 4 + mt) * 16 + fr;
    #pragma unroll
    for (int kt = 0; kt < 8; ++kt) {
      const int kb = kt * 32 + fk * 8;
      float4 f0 = *reinterpret_cast<const float4*>(&Whh_raw[j * 256 + kb]);
      float4 f1 = *reinterpret_cast<const float4*>(&Whh_raw[j * 256 + kb + 4]);
      float v[8] = {f0.x, f0.y, f0.z, f0.w, f1.x, f1.y, f1.z, f1.w};
      #pragma unroll
      for (int e = 0; e < 8; ++e) {
        if (kb + e == j) v[e] = NEGDIAG;
        short h = bf16_rne(v[e]);
        whi[mt][kt][e] = h;
        wlo[mt][kt][e] = bf16_rne(v[e] - bf16_to_f(h));
      }
    }
  }
  // ---- PIN to AGPRs: force each fragment into the acc half of the file ----
  #pragma unroll
  for (int mt = 0; mt < 4; ++mt)
    #pragma unroll
    for (int kt = 0; kt < 8; ++kt) {
      asm volatile("" : "+a"(whi[mt][kt]));
      asm volatile("" : "+a"(wlo[mt][kt]));
    }

  // ---- owner state: h, u for rows fq*4..fq*4+3 of each m-tile ----
  const int fq = lane >> 4;                    // same as fk; C row group
  const int jb = w * 64 + fq * 4;              // + mt*16
  float4 h4[4], u4[4];
  if (owner) {
    #pragma unroll
    for (int mt = 0; mt < 4; ++mt) {
      h4[mt] = *reinterpret_cast<const float4*>(&hidden_in[b * Hn + jb + mt * 16]);
      u4[mt] = *reinterpret_cast<const float4*>(&ubuf[(long)b * Hn + jb + mt * 16]);
    }
    // write rh[0] = relu(h0) hi/lo
    #pragma unroll
    for (int mt = 0; mt < 4; ++mt) {
      const int j0 = jb + mt * 16;
      short hh[4], ll[4];
      #pragma unroll
      for (int e = 0; e < 4; ++e) {
        float rv = fmaxf(h4[mt][e], 0.f);
        hh[e] = bf16_rne(rv);
        ll[e] = bf16_rne(rv - bf16_to_f(hh[e]));
      }
      *reinterpret_cast<uint2*>(&rh_s[0][0][j0]) = make_uint2(pack2(hh[0], hh[1]), pack2(hh[2], hh[3]));
      *reinterpret_cast<uint2*>(&rh_s[0][1][j0]) = make_uint2(pack2(ll[0], ll[1]), pack2(ll[2], ll[3]));
    }
  }
  __syncthreads();

  const float* u_ptr  = ubuf + ((long)Bn + b) * Hn + jb;   // t = 1
  float*       ys_ptr = ubuf + (long)b * Hn + jb;          // t = 0

  #pragma unroll 2
  for (int t = 0; t < Tn; ++t) {
    const int p = t & 1;
    // B fragments: broadcast reads (4 distinct 16B lines per instr)
    short8 bh[8], bl[8];
    #pragma unroll
    for (int kt = 0; kt < 8; ++kt) {
      bh[kt] = *reinterpret_cast<const short8*>(&rh_s[p][0][kt * 32 + fk * 8]);
      bl[kt] = *reinterpret_cast<const short8*>(&rh_s[p][1][kt * 32 + fk * 8]);
    }
    // prefetch next u under the MFMAs
    float4 un[4];
    if (owner && t < Tn - 1) {
      #pragma unroll
      for (int mt = 0; mt < 4; ++mt)
        un[mt] = *reinterpret_cast<const float4*>(u_ptr + mt * 16);
    }

    f32x4 a1[4], a2[4], a3[4];
    #pragma unroll
    for (int mt = 0; mt < 4; ++mt) {
      a1[mt] = (f32x4){0.f, 0.f, 0.f, 0.f};
      a2[mt] = (f32x4){0.f, 0.f, 0.f, 0.f};
      a3[mt] = (f32x4){0.f, 0.f, 0.f, 0.f};
    }
    #pragma unroll
    for (int kt = 0; kt < 8; ++kt)
      #pragma unroll
      for (int mt = 0; mt < 4; ++mt) {
        a1[mt] = __builtin_amdgcn_mfma_f32_16x16x32_bf16(whi[mt][kt], bh[kt], a1[mt], 0, 0, 0);
        a2[mt] = __builtin_amdgcn_mfma_f32_16x16x32_bf16(whi[mt][kt], bl[kt], a2[mt], 0, 0, 0);
        a3[mt] = __builtin_amdgcn_mfma_f32_16x16x32_bf16(wlo[mt][kt], bh[kt], a3[mt], 0, 0, 0);
      }

    if (owner) {
      const int p2 = p ^ 1;
      #pragma unroll
      for (int mt = 0; mt < 4; ++mt) {
        const int j0 = jb + mt * 16;
        float4 hn;
        short hh[4], ll[4];
        #pragma unroll
        for (int e = 0; e < 4; ++e) {
          float s = (a1[mt][e] + a2[mt][e]) + a3[mt][e];
          float v = fmaf(LEAK, h4[mt][e], u4[mt][e]) + s;
          v = fminf(fmaxf(v, -CLAMP_V), CLAMP_V);
          hn[e] = v;
          float rv = fmaxf(v, 0.f);
          hh[e] = bf16_rne(rv);
          ll[e] = bf16_rne(rv - bf16_to_f(hh[e]));
        }
        *reinterpret_cast<float4*>(ys_ptr + mt * 16) = hn;   // ys in place
        *reinterpret_cast<uint2*>(&rh_s[p2][0][j0]) = make_uint2(pack2(hh[0], hh[1]), pack2(hh[2], hh[3]));
        *reinterpret_cast<uint2*>(&rh_s[p2][1][j0]) = make_uint2(pack2(ll[0], ll[1]), pack2(ll[2], ll[3]));
        h4[mt] = hn;
        u4[mt] = un[mt];
      }
    }
    FAST_BARRIER();
    ys_ptr += Bn * Hn;
    u_ptr  += Bn * Hn;
  }

  if (owner) {
    #pragma unroll
    for (int mt = 0; mt < 4; ++mt)
      *reinterpret_cast<float4*>(&out[(long)Bn * Tn * 2 + b * Hn + jb + mt * 16]) = h4[mt];
  }
}

// ---------------------------------------------------------------------------
// G2: v = relu(ys @ W2^T + b2); y = v @ W3^T -> d_out. (unchanged, passing)
// ---------------------------------------------------------------------------
__global__ __launch_bounds__(512) void g_out(
    const float* __restrict__ ys, const float* __restrict__ W2,
    const float* __restrict__ b2, const float* __restrict__ W3,
    float* __restrict__ yout)
{
  __shared__ short Ah[128*SA], Al[128*SA], Bh[256*SA], Bl[256*SA];
  __shared__ float b2_s[256];
  __shared__ float w3_s[512];
  const int tid = threadIdx.x;
  const int r0  = blockIdx.x * 128;

  if (tid < 256) b2_s[tid] = b2[tid];
  if (tid < 512) w3_s[tid] = W3[tid];

  const int w    = tid >> 6, lane = tid & 63;
  const int wm   = w >> 2, wn = w & 3;
  const int fr   = lane & 15, fk = lane >> 4;
  f32x4 acc[4][4];
  #pragma unroll
  for (int a = 0; a < 4; ++a)
    #pragma unroll
    for (int c = 0; c < 4; ++c) acc[a][c] = (f32x4){0.f, 0.f, 0.f, 0.f};

  __syncthreads();

  for (int ks = 0; ks < 8; ++ks) {
    const int k0 = ks * 32;
    if (ks) __syncthreads();
    for (int c = tid; c < 1024; c += 512) {
      int rr = c >> 3, kc = (c & 7) * 4;
      float4 f = *reinterpret_cast<const float4*>(&ys[(long)(r0 + rr) * Hn + k0 + kc]);
      short h0 = bf16_rne(f.x), h1 = bf16_rne(f.y), h2 = bf16_rne(f.z), h3 = bf16_rne(f.w);
      short l0 = bf16_rne(f.x - bf16_to_f(h0)), l1 = bf16_rne(f.y - bf16_to_f(h1));
      short l2 = bf16_rne(f.z - bf16_to_f(h2)), l3 = bf16_rne(f.w - bf16_to_f(h3));
      int off = rr * SA + kc;
      *reinterpret_cast<uint2*>(&Ah[off]) = make_uint2(pack2(h0, h1), pack2(h2, h3));
      *reinterpret_cast<uint2*>(&Al[off]) = make_uint2(pack2(l0, l1), pack2(l2, l3));
    }
    for (int c = tid; c < 2048; c += 512) {
      int n = c >> 3, kc = (c & 7) * 4;
      float4 f = *reinterpret_cast<const float4*>(&W2[n * 256 + k0 + kc]);
      short h0 = bf16_rne(f.x), h1 = bf16_rne(f.y), h2 = bf16_rne(f.z), h3 = bf16_rne(f.w);
      short l0 = bf16_rne(f.x - bf16_to_f(h0)), l1 = bf16_rne(f.y - bf16_to_f(h1));
      short l2 = bf16_rne(f.z - bf16_to_f(h2)), l3 = bf16_rne(f.w - bf16_to_f(h3));
      int off = n * SA + kc;
      *reinterpret_cast<uint2*>(&Bh[off]) = make_uint2(pack2(h0, h1), pack2(h2, h3));
      *reinterpret_cast<uint2*>(&Bl[off]) = make_uint2(pack2(l0, l1), pack2(l2, l3));
    }
    __syncthreads();
    short8 bhf[4], blf[4];
    #pragma unroll
    for (int nf = 0; nf < 4; ++nf) {
      const int brow = wn * 64 + nf * 16 + fr;
      bhf[nf] = *reinterpret_cast<const short8*>(&Bh[brow * SA + fk * 8]);
      blf[nf] = *reinterpret_cast<const short8*>(&Bl[brow * SA + fk * 8]);
    }
    #pragma unroll
    for (int mf = 0; mf < 4; ++mf) {
      const int arow = wm * 64 + mf * 16 + fr;
      short8 ah = *reinterpret_cast<const short8*>(&Ah[arow * SA + fk * 8]);
      short8 al = *reinterpret_cast<const short8*>(&Al[arow * SA + fk * 8]);
      #pragma unroll
      for (int nf = 0; nf < 4; ++nf) {
        acc[mf][nf] = __builtin_amdgcn_mfma_f32_16x16x32_bf16(ah, bhf[nf], acc[mf][nf], 0, 0, 0);
        acc[mf][nf] = __builtin_amdgcn_mfma_f32_16x16x32_bf16(ah, blf[nf], acc[mf][nf], 0, 0, 0);
        acc[mf][nf] = __builtin_amdgcn_mfma_f32_16x16x32_bf16(al, bhf[nf], acc[mf][nf], 0, 0, 0);
      }
    }
  }

  float yp[4][4][2];
  #pragma unroll
  for (int mf = 0; mf < 4; ++mf)
    #pragma unroll
    for (int j = 0; j < 4; ++j) { yp[mf][j][0] = 0.f; yp[mf][j][1] = 0.f; }

  #pragma unroll
  for (int mf = 0; mf < 4; ++mf)
    #pragma unroll
    for (int nf = 0; nf < 4; ++nf) {
      const int n = wn * 64 + nf * 16 + fr;
      const float b2v = b2_s[n];
      const float w30 = w3_s[n], w31 = w3_s[256 + n];
      #pragma unroll
      for (int j = 0; j < 4; ++j) {
        float v = fmaxf(acc[mf][nf][j] + b2v, 0.f);
        yp[mf][j][0] = fmaf(v, w30, yp[mf][j][0]);
        yp[mf][j][1] = fmaf(v, w31, yp[mf][j][1]);
      }
    }
  #pragma unroll
  for (int off = 1; off < 16; off <<= 1) {
    #pragma unroll
    for (int mf = 0; mf < 4; ++mf)
      #pragma unroll
      for (int j = 0; j < 4; ++j) {
        yp[mf][j][0] += __shfl_xor(yp[mf][j][0], off);
        yp[mf][j][1] += __shfl_xor(yp[mf][j][1], off);
      }
  }

  __syncthreads();
  float* yred = reinterpret_cast<float*>(Ah);   // [128][2][4 wn]
  if (fr == 0) {
    #pragma unroll
    for (int mf = 0; mf < 4; ++mf)
      #pragma unroll
      for (int j = 0; j < 4; ++j) {
        int rl = wm * 64 + mf * 16 + (lane >> 4) * 4 + j;
        yred[(rl * 2 + 0) * 4 + wn] = yp[mf][j][0];
        yred[(rl * 2 + 1) * 4 + wn] = yp[mf][j][1];
      }
  }
  __syncthreads();
  if (tid < 256) {
    int rl = tid >> 1, a = tid & 1;
    const float* yr = &yred[(rl * 2 + a) * 4];
    float y = (yr[0] + yr[1]) + (yr[2] + yr[3]);
    int r = r0 + rl, b = r & 63, t = r >> 6;
    yout[((long)b * Tn + t) * 2 + a] = y;
  }
}

// ---------------------------------------------------------------------------
// Head: y -> softmax/mix -> out, in place. (unchanged, passing)
// ---------------------------------------------------------------------------
__global__ __launch_bounds__(256) void k_head(
    float* __restrict__ out, const float* __restrict__ Qs,
    const float* __restrict__ reward, const float* __restrict__ mix_w,
    const float* __restrict__ b3)
{
  const int idx = blockIdx.x * 256 + threadIdx.x;   // b*Tn + t
  if (idx >= Bn * Tn) return;
  const long base = (long)idx * 2;
  float y0 = out[base]     + b3[0];
  float y1 = out[base + 1] + b3[1];
  float z0 = (y0 == 0.f) ? EPS_V : 0.f;
  float z1 = (y1 == 0.f) ? EPS_V : 0.f;

  float m  = fmaxf(y0, y1);
  float e0 = expf(y0 - m), e1 = expf(y1 - m), es = e0 + e1;
  float sp0 = e0 / es, sp1 = e1 / es;

  float q0 = Qs[base], q1 = Qs[base + 1];
  float mq = fmaxf(q0, q1);
  float f0 = expf(q0 - mq), f1 = expf(q1 - mq), fs = f0 + f1;
  float sq0 = f0 / fs, sq1 = f1 / fs;

  int ri = (int)reward[base];
  float m0 = fminf(fmaxf(mix_w[ri * 2 + 0], -1.f), 1.f);
  float m1 = fminf(fmaxf(mix_w[ri * 2 + 1], -1.f), 1.f);
  float den = fabsf(m0) + fabsf(m1);
  float s0 = m0 / den, s1 = m1 / den;

  out[base]     = expf(s0 * logf(sp0 + z0) + s1 * logf(sq0 + z0));
  out[base + 1] = expf(s0 * logf(sp1 + z1) + s1 * logf(sq1 + z1));
}

// ---------------------------------------------------------------------------
extern "C" void kernel_launch(void* const* d_in, const int* in_sizes, int n_in,
                              void* d_out, int out_size, void* d_ws, size_t ws_size,
                              hipStream_t stream)
{
  const float* state       = (const float*)d_in[0];
  const float* last_action = (const float*)d_in[1];
  const float* reward      = (const float*)d_in[2];
  const float* hidden_in   = (const float*)d_in[3];
  const float* W1          = (const float*)d_in[4];
  const float* b1          = (const float*)d_in[5];
  const float* Wih         = (const float*)d_in[6];
  const float* Whh_raw     = (const float*)d_in[7];
  const float* W2          = (const float*)d_in[8];
  const float* b2          = (const float*)d_in[9];
  const float* W3          = (const float*)d_in[10];
  const float* b3          = (const float*)d_in[11];
  const float* Qs          = (const float*)d_in[12];
  const float* mix_w       = (const float*)d_in[13];
  float* out = (float*)d_out;
  float* u   = (float*)d_ws;   // (T*B, H) fp32 = 128 MiB; ys overwrites in place

  const int nrows = Tn * Bn;                 // 131072
  g_u   <<<nrows / 128, 512, 0, stream>>>(reward, state, last_action, W1, b1, Wih, u);
  k_scan<<<Bn,           256, 0, stream>>>(Whh_raw, hidden_in, u, out);
  g_out <<<nrows / 128, 512, 0, stream>>>(u, W2, b2, W3, out);
  k_head<<<nrows / 256, 256, 0, stream>>>(out, Qs, reward, mix_w, b3);
}

// Round 13
// 1455.788 us; speedup vs baseline: 2.0262x; 2.0262x over previous
//
#include <hip/hip_runtime.h>
#include <hip/hip_bf16.h>
#include <math.h>

#define Bn 64
#define Tn 2048
#define Hn 256

constexpr float LEAK    = 0.5f;     // 1 - 1/TAU
constexpr float NEGDIAG = -0.5f;    // -1/TAU
constexpr float CLAMP_V = 1000.0f;
constexpr float EPS_V   = 1e-4f;

typedef __attribute__((ext_vector_type(8))) short  short8;  // 8 bf16 (4 VGPR)
typedef __attribute__((ext_vector_type(4))) float  f32x4;
typedef __attribute__((ext_vector_type(2))) float  f32x2;

#define FAST_BARRIER() do {                                   \
    asm volatile("s_waitcnt lgkmcnt(0)" ::: "memory");        \
    __builtin_amdgcn_s_barrier();                             \
    asm volatile("" ::: "memory");                            \
  } while (0)

__device__ inline short bf16_rne(float x) {
  __hip_bfloat16 h = __float2bfloat16(x);
  return *reinterpret_cast<short*>(&h);
}
__device__ inline float bf16_to_f(short s) {
  union { unsigned u; float f; } c; c.u = ((unsigned)(unsigned short)s) << 16;
  return c.f;
}
__device__ inline unsigned pack2(short a, short b) {
  return (unsigned)(unsigned short)a | ((unsigned)(unsigned short)b << 16);
}
// packed dual fp32 FMA: a += x*y
__device__ inline void pkfma(f32x2& a, f32x2 x, f32x2 y) {
  asm("v_pk_fma_f32 %0, %1, %2, %0" : "+v"(a) : "v"(x), "v"(y));
}
#define SWZ(x, imm) __int_as_float(__builtin_amdgcn_ds_swizzle(__float_as_int(x), (imm)))

// DPP receive: value of `x` from the DPP-selected partner lane (VALU pipe)
template <int CTRL>
__device__ __forceinline__ float dpp_recv(float x) {
  return __int_as_float(
      __builtin_amdgcn_update_dpp(0, __float_as_int(x), CTRL, 0xF, 0xF, true));
}

// LDS row stride for bf16 tiles: 32 k + 8 pad = 40 shorts (80 B, 16B-multiple)
#define SA 40

// ---------------------------------------------------------------------------
// G1: u = relu(inp8 @ W1^T + b1) @ Wih^T, MFMA bf16 hi/lo. (unchanged, passing)
// ---------------------------------------------------------------------------
__global__ __launch_bounds__(512) void g_u(
    const float* __restrict__ reward, const float* __restrict__ state,
    const float* __restrict__ last_action, const float* __restrict__ W1,
    const float* __restrict__ b1, const float* __restrict__ Wih,
    float* __restrict__ u)
{
  __shared__ short Ah[128*SA], Al[128*SA], Bh[256*SA], Bl[256*SA];
  __shared__ __align__(16) float inp_s[128][8];
  __shared__ __align__(16) float w1_s[256][8];
  __shared__ float b1_s[256];
  const int tid = threadIdx.x;
  const int r0  = blockIdx.x * 128;

  for (int idx = tid; idx < 2048; idx += 512) ((float*)w1_s)[idx] = W1[idx];
  if (tid < 256) b1_s[tid] = b1[tid];
  for (int idx = tid; idx < 1024; idx += 512) {
    int rr = idx >> 3, i = idx & 7;
    int r = r0 + rr, b = r & 63, t = r >> 6;
    long base = (long)b * Tn + t;
    float v;
    if (i < 2)      v = reward[base * 2 + i];
    else if (i < 6) v = state[base * 4 + (i - 2)];
    else            v = last_action[base * 2 + (i - 6)];
    inp_s[rr][i] = v;
  }

  const int w    = tid >> 6, lane = tid & 63;
  const int wm   = w >> 2, wn = w & 3;
  const int fr   = lane & 15, fk = lane >> 4;
  f32x4 acc[4][4];
  #pragma unroll
  for (int a = 0; a < 4; ++a)
    #pragma unroll
    for (int c = 0; c < 4; ++c) acc[a][c] = (f32x4){0.f, 0.f, 0.f, 0.f};

  __syncthreads();

  for (int ks = 0; ks < 8; ++ks) {
    const int k0 = ks * 32;
    if (ks) __syncthreads();
    for (int p = tid; p < 2048; p += 512) {
      int rr = p >> 4, kp = (p & 15) * 2;
      int k = k0 + kp;
      float4 iv0 = *reinterpret_cast<const float4*>(&inp_s[rr][0]);
      float4 iv1 = *reinterpret_cast<const float4*>(&inp_s[rr][4]);
      float4 wa0 = *reinterpret_cast<const float4*>(&w1_s[k][0]);
      float4 wa1 = *reinterpret_cast<const float4*>(&w1_s[k][4]);
      float4 wb0 = *reinterpret_cast<const float4*>(&w1_s[k+1][0]);
      float4 wb1 = *reinterpret_cast<const float4*>(&w1_s[k+1][4]);
      float s0 = b1_s[k], s1 = b1_s[k+1];
      s0 = fmaf(iv0.x, wa0.x, s0); s0 = fmaf(iv0.y, wa0.y, s0);
      s0 = fmaf(iv0.z, wa0.z, s0); s0 = fmaf(iv0.w, wa0.w, s0);
      s0 = fmaf(iv1.x, wa1.x, s0); s0 = fmaf(iv1.y, wa1.y, s0);
      s0 = fmaf(iv1.z, wa1.z, s0); s0 = fmaf(iv1.w, wa1.w, s0);
      s1 = fmaf(iv0.x, wb0.x, s1); s1 = fmaf(iv0.y, wb0.y, s1);
      s1 = fmaf(iv0.z, wb0.z, s1); s1 = fmaf(iv0.w, wb0.w, s1);
      s1 = fmaf(iv1.x, wb1.x, s1); s1 = fmaf(iv1.y, wb1.y, s1);
      s1 = fmaf(iv1.z, wb1.z, s1); s1 = fmaf(iv1.w, wb1.w, s1);
      float v0 = fmaxf(s0, 0.f), v1 = fmaxf(s1, 0.f);
      short h0 = bf16_rne(v0), h1 = bf16_rne(v1);
      short l0 = bf16_rne(v0 - bf16_to_f(h0)), l1 = bf16_rne(v1 - bf16_to_f(h1));
      int off = rr * SA + kp;
      *reinterpret_cast<unsigned*>(&Ah[off]) = pack2(h0, h1);
      *reinterpret_cast<unsigned*>(&Al[off]) = pack2(l0, l1);
    }
    for (int c = tid; c < 2048; c += 512) {
      int n = c >> 3, kc = (c & 7) * 4;
      float4 f = *reinterpret_cast<const float4*>(&Wih[n * 256 + k0 + kc]);
      short h0 = bf16_rne(f.x), h1 = bf16_rne(f.y), h2 = bf16_rne(f.z), h3 = bf16_rne(f.w);
      short l0 = bf16_rne(f.x - bf16_to_f(h0)), l1 = bf16_rne(f.y - bf16_to_f(h1));
      short l2 = bf16_rne(f.z - bf16_to_f(h2)), l3 = bf16_rne(f.w - bf16_to_f(h3));
      int off = n * SA + kc;
      *reinterpret_cast<uint2*>(&Bh[off]) = make_uint2(pack2(h0, h1), pack2(h2, h3));
      *reinterpret_cast<uint2*>(&Bl[off]) = make_uint2(pack2(l0, l1), pack2(l2, l3));
    }
    __syncthreads();
    short8 bhf[4], blf[4];
    #pragma unroll
    for (int nf = 0; nf < 4; ++nf) {
      const int brow = wn * 64 + nf * 16 + fr;
      bhf[nf] = *reinterpret_cast<const short8*>(&Bh[brow * SA + fk * 8]);
      blf[nf] = *reinterpret_cast<const short8*>(&Bl[brow * SA + fk * 8]);
    }
    #pragma unroll
    for (int mf = 0; mf < 4; ++mf) {
      const int arow = wm * 64 + mf * 16 + fr;
      short8 ah = *reinterpret_cast<const short8*>(&Ah[arow * SA + fk * 8]);
      short8 al = *reinterpret_cast<const short8*>(&Al[arow * SA + fk * 8]);
      #pragma unroll
      for (int nf = 0; nf < 4; ++nf) {
        acc[mf][nf] = __builtin_amdgcn_mfma_f32_16x16x32_bf16(ah, bhf[nf], acc[mf][nf], 0, 0, 0);
        acc[mf][nf] = __builtin_amdgcn_mfma_f32_16x16x32_bf16(ah, blf[nf], acc[mf][nf], 0, 0, 0);
        acc[mf][nf] = __builtin_amdgcn_mfma_f32_16x16x32_bf16(al, bhf[nf], acc[mf][nf], 0, 0, 0);
      }
    }
  }
  #pragma unroll
  for (int mf = 0; mf < 4; ++mf) {
    const int rbase = r0 + wm * 64 + mf * 16 + (lane >> 4) * 4;
    #pragma unroll
    for (int nf = 0; nf < 4; ++nf) {
      const int n = wn * 64 + nf * 16 + fr;
      #pragma unroll
      for (int j = 0; j < 4; ++j)
        u[(long)(rbase + j) * Hn + n] = acc[mf][nf][j];
    }
  }
}

// ---------------------------------------------------------------------------
// K2 v12: round-7 structure (PASSED, 1276us) + loop-carried register pinning.
// The allocator has two escape hatches from keeping the 128 weight floats
// resident: rematerialize the loads (legal via __restrict__ invariance;
// what r7 did -> ~128KB/step L1 reload = the measured floor) or scratch-spill
// (what r9's volatile produced, same traffic). The empty per-iteration
// asm "+v" pins redefine each weight register with an opaque value, making
// remat ILLEGAL (value != provably the load), so the only options are
// register-resident (budget 256 at (512,2), need ~153) or per-step scratch
// round-trip (costed as expensive). Everything else byte-identical to r7.
// ---------------------------------------------------------------------------
__global__ __launch_bounds__(512, 2) void k_scan(
    const float* __restrict__ Whh_raw, const float* __restrict__ hidden_in,
    float* __restrict__ ubuf, float* __restrict__ out)
{
  __shared__ __align__(16) float rh[2][256];
  const int tid = threadIdx.x;
  const int w = tid >> 6;                       // 0..7
  const int l = tid & 63;
  const int g = (l & 3) | ((l >> 1) & 0x1C);    // k-group: bits {0,1,3,4,5}
  const int o = (l >> 2) & 1;                   // output half
  const int b = blockIdx.x;
  // XOR key = bitrev4(g&15): slot s holds output m = s ^ key
  const int key = ((g & 1) << 3) | ((g & 2) << 1) | ((g & 4) >> 1) | ((g & 8) >> 3);

  // weights: slot s, pair i -> output j = 32w+16o+(s^key), k = 8g+2i(+1)
  f32x2 w2[16][4];
  #pragma unroll
  for (int s = 0; s < 16; ++s) {
    const int j = (w << 5) + (o << 4) + (s ^ key);
    #pragma unroll
    for (int i = 0; i < 4; ++i) {
      const int k = (g << 3) + 2 * i;
      float a = Whh_raw[j * 256 + k];
      float c = Whh_raw[j * 256 + k + 1];
      if (k == j)     a = NEGDIAG;
      if (k + 1 == j) c = NEGDIAG;
      w2[s][i] = (f32x2){a, c};
    }
  }

  const bool owner = (l < 32);
  const int j_own = (w << 5) + (o << 4) + key;

  // swizzle: logical k stored at row*32 + ((k&31) + 4*row)&31, row = k>>5
  const int row  = g >> 2;
  const int srot = (((g & 3) << 3) + (row << 2)) & 31;
  const int rd1  = row * 32 + srot;
  const int rd2  = row * 32 + ((srot + 4) & 31);
  const int wrow = j_own >> 5;
  const int wr   = wrow * 32 + (((j_own & 31) + (wrow << 2)) & 31);

  float h = 0.f, u_c = 0.f, u_n = 0.f;
  if (owner) {
    h   = hidden_in[b * Hn + j_own];
    u_c = ubuf[(long)b * Hn + j_own];                    // u[t=0]
    u_n = ubuf[((long)Bn + b) * Hn + j_own];             // u[t=1]
  }
  const float* u_ptr  = ubuf + ((long)2 * Bn + b) * Hn + j_own;   // t = 2
  float*       ys_ptr = ubuf + (long)b * Hn + j_own;              // t = 0

#define SCAN_STEP(P)                                                         \
  {                                                                          \
    if (owner) rh[P][wr] = fmaxf(h, 0.f);                                    \
    FAST_BARRIER();                                                          \
    float u_pf = 0.f;                                                        \
    if (owner && t + 2 < Tn) u_pf = *u_ptr;                                  \
    const float4 ra = *reinterpret_cast<const float4*>(&rh[P][rd1]);         \
    const float4 rb = *reinterpret_cast<const float4*>(&rh[P][rd2]);         \
    const f32x2 rp0 = {ra.x, ra.y}, rp1 = {ra.z, ra.w};                      \
    const f32x2 rp2 = {rb.x, rb.y}, rp3 = {rb.z, rb.w};                      \
    float v[16];                                                             \
    _Pragma("unroll")                                                        \
    for (int s = 0; s < 16; ++s) {                                           \
      f32x2 c = {0.f, 0.f};                                                  \
      pkfma(c, rp0, w2[s][0]); pkfma(c, rp1, w2[s][1]);                      \
      pkfma(c, rp2, w2[s][2]); pkfma(c, rp3, w2[s][3]);                      \
      v[s] = c.x + c.y;                                                      \
    }                                                                        \
    _Pragma("unroll")                                                        \
    for (int s = 0; s < 8; ++s) v[s] += dpp_recv<0xB1>(v[s + 8]);            \
    _Pragma("unroll")                                                        \
    for (int s = 0; s < 4; ++s) v[s] += dpp_recv<0x4E>(v[s + 4]);            \
    _Pragma("unroll")                                                        \
    for (int s = 0; s < 2; ++s) v[s] += dpp_recv<0x128>(v[s + 2]);           \
    v[0] += SWZ(v[1], 0x401F);                                               \
    {                                                                        \
      float pa = v[0], pb = v[0];                                            \
      asm("v_permlane32_swap_b32 %0, %1" : "+v"(pa), "+v"(pb));              \
      v[0] = pa + pb;                                                        \
    }                                                                        \
    if (owner) {                                                             \
      float hn = fmaf(LEAK, h, u_c) + v[0];                                  \
      hn = fminf(fmaxf(hn, -CLAMP_V), CLAMP_V);                              \
      *ys_ptr = hn;                                                          \
      h = hn; u_c = u_n; u_n = u_pf;                                         \
    }                                                                        \
    ys_ptr += Bn * Hn;                                                       \
    u_ptr  += Bn * Hn;                                                       \
  }

  for (int tt = 0; tt < Tn; tt += 2) {
    // loop-carried pin: weights become opaque register state each iteration
    // -> rematerialization from Whh_raw is illegal, residency forced.
    #pragma unroll
    for (int s = 0; s < 16; ++s)
      asm volatile("" : "+v"(w2[s][0]), "+v"(w2[s][1]),
                        "+v"(w2[s][2]), "+v"(w2[s][3]));
    { const int t = tt;     SCAN_STEP(0) }
    { const int t = tt + 1; SCAN_STEP(1) }
  }
#undef SCAN_STEP

  if (owner) out[(long)Bn * Tn * 2 + b * Hn + j_own] = h;
}

// ---------------------------------------------------------------------------
// G2: v = relu(ys @ W2^T + b2); y = v @ W3^T -> d_out. (unchanged, passing)
// ---------------------------------------------------------------------------
__global__ __launch_bounds__(512) void g_out(
    const float* __restrict__ ys, const float* __restrict__ W2,
    const float* __restrict__ b2, const float* __restrict__ W3,
    float* __restrict__ yout)
{
  __shared__ short Ah[128*SA], Al[128*SA], Bh[256*SA], Bl[256*SA];
  __shared__ float b2_s[256];
  __shared__ float w3_s[512];
  const int tid = threadIdx.x;
  const int r0  = blockIdx.x * 128;

  if (tid < 256) b2_s[tid] = b2[tid];
  if (tid < 512) w3_s[tid] = W3[tid];

  const int w    = tid >> 6, lane = tid & 63;
  const int wm   = w >> 2, wn = w & 3;
  const int fr   = lane & 15, fk = lane >> 4;
  f32x4 acc[4][4];
  #pragma unroll
  for (int a = 0; a < 4; ++a)
    #pragma unroll
    for (int c = 0; c < 4; ++c) acc[a][c] = (f32x4){0.f, 0.f, 0.f, 0.f};

  __syncthreads();

  for (int ks = 0; ks < 8; ++ks) {
    const int k0 = ks * 32;
    if (ks) __syncthreads();
    for (int c = tid; c < 1024; c += 512) {
      int rr = c >> 3, kc = (c & 7) * 4;
      float4 f = *reinterpret_cast<const float4*>(&ys[(long)(r0 + rr) * Hn + k0 + kc]);
      short h0 = bf16_rne(f.x), h1 = bf16_rne(f.y), h2 = bf16_rne(f.z), h3 = bf16_rne(f.w);
      short l0 = bf16_rne(f.x - bf16_to_f(h0)), l1 = bf16_rne(f.y - bf16_to_f(h1));
      short l2 = bf16_rne(f.z - bf16_to_f(h2)), l3 = bf16_rne(f.w - bf16_to_f(h3));
      int off = rr * SA + kc;
      *reinterpret_cast<uint2*>(&Ah[off]) = make_uint2(pack2(h0, h1), pack2(h2, h3));
      *reinterpret_cast<uint2*>(&Al[off]) = make_uint2(pack2(l0, l1), pack2(l2, l3));
    }
    for (int c = tid; c < 2048; c += 512) {
      int n = c >> 3, kc = (c & 7) * 4;
      float4 f = *reinterpret_cast<const float4*>(&W2[n * 256 + k0 + kc]);
      short h0 = bf16_rne(f.x), h1 = bf16_rne(f.y), h2 = bf16_rne(f.z), h3 = bf16_rne(f.w);
      short l0 = bf16_rne(f.x - bf16_to_f(h0)), l1 = bf16_rne(f.y - bf16_to_f(h1));
      short l2 = bf16_rne(f.z - bf16_to_f(h2)), l3 = bf16_rne(f.w - bf16_to_f(h3));
      int off = n * SA + kc;
      *reinterpret_cast<uint2*>(&Bh[off]) = make_uint2(pack2(h0, h1), pack2(h2, h3));
      *reinterpret_cast<uint2*>(&Bl[off]) = make_uint2(pack2(l0, l1), pack2(l2, l3));
    }
    __syncthreads();
    short8 bhf[4], blf[4];
    #pragma unroll
    for (int nf = 0; nf < 4; ++nf) {
      const int brow = wn * 64 + nf * 16 + fr;
      bhf[nf] = *reinterpret_cast<const short8*>(&Bh[brow * SA + fk * 8]);
      blf[nf] = *reinterpret_cast<const short8*>(&Bl[brow * SA + fk * 8]);
    }
    #pragma unroll
    for (int mf = 0; mf < 4; ++mf) {
      const int arow = wm * 64 + mf * 16 + fr;
      short8 ah = *reinterpret_cast<const short8*>(&Ah[arow * SA + fk * 8]);
      short8 al = *reinterpret_cast<const short8*>(&Al[arow * SA + fk * 8]);
      #pragma unroll
      for (int nf = 0; nf < 4; ++nf) {
        acc[mf][nf] = __builtin_amdgcn_mfma_f32_16x16x32_bf16(ah, bhf[nf], acc[mf][nf], 0, 0, 0);
        acc[mf][nf] = __builtin_amdgcn_mfma_f32_16x16x32_bf16(ah, blf[nf], acc[mf][nf], 0, 0, 0);
        acc[mf][nf] = __builtin_amdgcn_mfma_f32_16x16x32_bf16(al, bhf[nf], acc[mf][nf], 0, 0, 0);
      }
    }
  }

  float yp[4][4][2];
  #pragma unroll
  for (int mf = 0; mf < 4; ++mf)
    #pragma unroll
    for (int j = 0; j < 4; ++j) { yp[mf][j][0] = 0.f; yp[mf][j][1] = 0.f; }

  #pragma unroll
  for (int mf = 0; mf < 4; ++mf)
    #pragma unroll
    for (int nf = 0; nf < 4; ++nf) {
      const int n = wn * 64 + nf * 16 + fr;
      const float b2v = b2_s[n];
      const float w30 = w3_s[n], w31 = w3_s[256 + n];
      #pragma unroll
      for (int j = 0; j < 4; ++j) {
        float v = fmaxf(acc[mf][nf][j] + b2v, 0.f);
        yp[mf][j][0] = fmaf(v, w30, yp[mf][j][0]);
        yp[mf][j][1] = fmaf(v, w31, yp[mf][j][1]);
      }
    }
  #pragma unroll
  for (int off = 1; off < 16; off <<= 1) {
    #pragma unroll
    for (int mf = 0; mf < 4; ++mf)
      #pragma unroll
      for (int j = 0; j < 4; ++j) {
        yp[mf][j][0] += __shfl_xor(yp[mf][j][0], off);
        yp[mf][j][1] += __shfl_xor(yp[mf][j][1], off);
      }
  }

  __syncthreads();
  float* yred = reinterpret_cast<float*>(Ah);   // [128][2][4 wn]
  if (fr == 0) {
    #pragma unroll
    for (int mf = 0; mf < 4; ++mf)
      #pragma unroll
      for (int j = 0; j < 4; ++j) {
        int rl = wm * 64 + mf * 16 + (lane >> 4) * 4 + j;
        yred[(rl * 2 + 0) * 4 + wn] = yp[mf][j][0];
        yred[(rl * 2 + 1) * 4 + wn] = yp[mf][j][1];
      }
  }
  __syncthreads();
  if (tid < 256) {
    int rl = tid >> 1, a = tid & 1;
    const float* yr = &yred[(rl * 2 + a) * 4];
    float y = (yr[0] + yr[1]) + (yr[2] + yr[3]);
    int r = r0 + rl, b = r & 63, t = r >> 6;
    yout[((long)b * Tn + t) * 2 + a] = y;
  }
}

// ---------------------------------------------------------------------------
// Head: y -> softmax/mix -> out, in place. (unchanged, passing)
// ---------------------------------------------------------------------------
__global__ __launch_bounds__(256) void k_head(
    float* __restrict__ out, const float* __restrict__ Qs,
    const float* __restrict__ reward, const float* __restrict__ mix_w,
    const float* __restrict__ b3)
{
  const int idx = blockIdx.x * 256 + threadIdx.x;   // b*Tn + t
  if (idx >= Bn * Tn) return;
  const long base = (long)idx * 2;
  float y0 = out[base]     + b3[0];
  float y1 = out[base + 1] + b3[1];
  float z0 = (y0 == 0.f) ? EPS_V : 0.f;
  float z1 = (y1 == 0.f) ? EPS_V : 0.f;

  float m  = fmaxf(y0, y1);
  float e0 = expf(y0 - m), e1 = expf(y1 - m), es = e0 + e1;
  float sp0 = e0 / es, sp1 = e1 / es;

  float q0 = Qs[base], q1 = Qs[base + 1];
  float mq = fmaxf(q0, q1);
  float f0 = expf(q0 - mq), f1 = expf(q1 - mq), fs = f0 + f1;
  float sq0 = f0 / fs, sq1 = f1 / fs;

  int ri = (int)reward[base];
  float m0 = fminf(fmaxf(mix_w[ri * 2 + 0], -1.f), 1.f);
  float m1 = fminf(fmaxf(mix_w[ri * 2 + 1], -1.f), 1.f);
  float den = fabsf(m0) + fabsf(m1);
  float s0 = m0 / den, s1 = m1 / den;

  out[base]     = expf(s0 * logf(sp0 + z0) + s1 * logf(sq0 + z0));
  out[base + 1] = expf(s0 * logf(sp1 + z1) + s1 * logf(sq1 + z1));
}

// ---------------------------------------------------------------------------
extern "C" void kernel_launch(void* const* d_in, const int* in_sizes, int n_in,
                              void* d_out, int out_size, void* d_ws, size_t ws_size,
                              hipStream_t stream)
{
  const float* state       = (const float*)d_in[0];
  const float* last_action = (const float*)d_in[1];
  const float* reward      = (const float*)d_in[2];
  const float* hidden_in   = (const float*)d_in[3];
  const float* W1          = (const float*)d_in[4];
  const float* b1          = (const float*)d_in[5];
  const float* Wih         = (const float*)d_in[6];
  const float* Whh_raw     = (const float*)d_in[7];
  const float* W2          = (const float*)d_in[8];
  const float* b2          = (const float*)d_in[9];
  const float* W3          = (const float*)d_in[10];
  const float* b3          = (const float*)d_in[11];
  const float* Qs          = (const float*)d_in[12];
  const float* mix_w       = (const float*)d_in[13];
  float* out = (float*)d_out;
  float* u   = (float*)d_ws;   // (T*B, H) fp32 = 128 MiB; ys overwrites in place

  const int nrows = Tn * Bn;                 // 131072
  g_u   <<<nrows / 128, 512, 0, stream>>>(reward, state, last_action, W1, b1, Wih, u);
  k_scan<<<Bn,           512, 0, stream>>>(Whh_raw, hidden_in, u, out);
  g_out <<<nrows / 128, 512, 0, stream>>>(u, W2, b2, W3, out);
  k_head<<<nrows / 256, 256, 0, stream>>>(out, Qs, reward, mix_w, b3);
}